// Round 5
// baseline (817.896 us; speedup 1.0000x reference)
//
#include <hip/hip_runtime.h>
#include <hip/hip_fp16.h>

#define N_ATOMS   50000
#define ATOM_FDIM 133
#define HIDDEN    128
#define DEPTH     3
#define N_EDGES   800000
#define N_MOLS    1024
#define BN_EPS    1e-5f
#define K_IN_PAD  160   // 133 padded to 5*32
#define NG        4     // CSR groups (XCD-affine via blockIdx&3)

typedef _Float16 f16x8 __attribute__((ext_vector_type(8)));
typedef float    f32x4 __attribute__((ext_vector_type(4)));

struct __align__(8) half4pack { __half2 a, b; };

// ---------------- histogram (grouped) ----------------
__global__ void hist_kernel(const int* __restrict__ idx, int n, int* __restrict__ cnt) {
    int i = blockIdx.x * blockDim.x + threadIdx.x;
    int g = blockIdx.x & (NG - 1);
    if (i < n) atomicAdd(&cnt[g * N_ATOMS + idx[i]], 1);
}

// ---------------- hierarchical exclusive scan ----------------
__global__ void scan_block_kernel(const int* __restrict__ in, int* __restrict__ out,
                                  int* __restrict__ bsum, int n) {
    __shared__ int buf[256];
    int i = blockIdx.x * 256 + threadIdx.x;
    int v = (i < n) ? in[i] : 0;
    buf[threadIdx.x] = v;
    __syncthreads();
    #pragma unroll
    for (int off = 1; off < 256; off <<= 1) {
        int t = (threadIdx.x >= off) ? buf[threadIdx.x - off] : 0;
        __syncthreads();
        buf[threadIdx.x] += t;
        __syncthreads();
    }
    if (i < n) out[i] = buf[threadIdx.x] - v;
    if (threadIdx.x == 255) bsum[blockIdx.x] = buf[255];
}

__global__ void scan_top_kernel(int* __restrict__ bsum, int nb) {
    __shared__ int buf[256];
    int v = (threadIdx.x < nb) ? bsum[threadIdx.x] : 0;
    buf[threadIdx.x] = v;
    __syncthreads();
    #pragma unroll
    for (int off = 1; off < 256; off <<= 1) {
        int t = (threadIdx.x >= off) ? buf[threadIdx.x - off] : 0;
        __syncthreads();
        buf[threadIdx.x] += t;
        __syncthreads();
    }
    if (threadIdx.x < nb) bsum[threadIdx.x] = buf[threadIdx.x] - v;
}

// rowptr[i] = p1[i] + p2[i/256] + b2[i/65536]; also init wcur
__global__ void scan_add2_kernel(const int* __restrict__ p1, const int* __restrict__ p2,
                                 const int* __restrict__ b2,
                                 int* __restrict__ rowptr, int* __restrict__ wcur,
                                 int n, int total) {
    int i = blockIdx.x * 256 + threadIdx.x;
    if (i < n) {
        int v = p1[i] + p2[i >> 8] + b2[i >> 16];
        rowptr[i] = v;
        wcur[i]   = v;
    }
    if (i == 0) rowptr[n] = total;
}

// ---------------- CSR fill (grouped; col as uint16: src < 65536) ----------------
__global__ void fill_csr_kernel(const int* __restrict__ src, const int* __restrict__ tgt,
                                int n, int* __restrict__ wcur, unsigned short* __restrict__ col) {
    int e = blockIdx.x * blockDim.x + threadIdx.x;
    int g = blockIdx.x & (NG - 1);
    if (e < n) {
        int t = tgt[e];
        int p = atomicAdd(&wcur[g * N_ATOMS + t], 1);
        col[p] = (unsigned short)src[e];
    }
}

// ---------------- fused setup: atoms->fp16(pad), weights->fp16^T, stats zero, mol offsets ----
__global__ void setup_kernel(const float* __restrict__ f,
                             const float* __restrict__ W_in,
                             const float* __restrict__ W1,
                             const float* __restrict__ W2,
                             const int* __restrict__ seg,
                             __half* __restrict__ Ah, __half* __restrict__ Wt,
                             float* __restrict__ stats, int* __restrict__ moloff)
{
    const int NCH = N_ATOMS * (K_IN_PAD / 4);
    const int NW4 = (128 * K_IN_PAD + 2 * DEPTH * 128 * 128) / 4;
    int i = blockIdx.x * 256 + threadIdx.x;
    if (i < NCH) {
        int row = i / (K_IN_PAD / 4);
        int c4  = (i - row * (K_IN_PAD / 4)) * 4;
        float v[4];
        #pragma unroll
        for (int u = 0; u < 4; ++u) {
            int k = c4 + u;
            v[u] = (k < ATOM_FDIM) ? f[(size_t)row * ATOM_FDIM + k] : 0.f;
        }
        half4pack p;
        p.a = __float22half2_rn(make_float2(v[0], v[1]));
        p.b = __float22half2_rn(make_float2(v[2], v[3]));
        *(half4pack*)&Ah[(size_t)row * K_IN_PAD + c4] = p;
        return;
    }
    int j = i - NCH;
    if (j < NW4) {
        float v[4];
        #pragma unroll
        for (int u = 0; u < 4; ++u) {
            int e = j * 4 + u;
            if (e < 128 * K_IN_PAD) {
                int n = e / K_IN_PAD, k = e - n * K_IN_PAD;
                v[u] = (k < ATOM_FDIM) ? W_in[(size_t)k * 128 + n] : 0.f;
            } else if (e < 128 * K_IN_PAD + DEPTH * 128 * 128) {
                int q = e - 128 * K_IN_PAD;
                int d = q >> 14, r = q & 16383;
                int n = r >> 7, k = r & 127;
                v[u] = W1[((size_t)d * 128 + k) * 128 + n];
            } else {
                int q = e - 128 * K_IN_PAD - DEPTH * 128 * 128;
                int d = q >> 14, r = q & 16383;
                int n = r >> 7, k = r & 127;
                v[u] = W2[((size_t)d * 128 + k) * 128 + n];
            }
        }
        half4pack p;
        p.a = __float22half2_rn(make_float2(v[0], v[1]));
        p.b = __float22half2_rn(make_float2(v[2], v[3]));
        *(half4pack*)&Wt[j * 4] = p;
        return;
    }
    int m = j - NW4;
    if (m < DEPTH * 256) stats[m] = 0.f;
    if (m <= N_MOLS) {
        int lo = 0, hi = N_ATOMS;
        while (lo < hi) {
            int mid = (lo + hi) >> 1;
            if (seg[mid] < m) lo = mid + 1; else hi = mid;
        }
        moloff[m] = lo;
    }
}

#define LDS_S 40   // padded stride (halves) per 32-half k-chunk row

// ---------------- MFMA GEMM, K variable (input projection) ----------------
template<bool RELU>
__global__ __launch_bounds__(256, 2) void mfma_gemm(
    const __half* __restrict__ A, const __half* __restrict__ Bt,
    const float* __restrict__ bias, __half* __restrict__ C, int M, int K)
{
    __shared__ __align__(16) __half As[128 * LDS_S];
    __shared__ __align__(16) __half Bs[128 * LDS_S];

    const int t = threadIdx.x;
    const int w = t >> 6, lane = t & 63;
    const int wm = w >> 1, wn = w & 1;
    const int l15 = lane & 15, quad = lane >> 4;
    const int row0 = blockIdx.x * 128;

    f32x4 acc[4][4];
    #pragma unroll
    for (int mt = 0; mt < 4; ++mt)
        #pragma unroll
        for (int nt = 0; nt < 4; ++nt) acc[mt][nt] = (f32x4){0.f, 0.f, 0.f, 0.f};

    for (int k0 = 0; k0 < K; k0 += 32) {
        #pragma unroll
        for (int i = 0; i < 2; ++i) {
            int c = t * 2 + i;
            int r = c >> 2, o = c & 3;
            int row = row0 + r;
            uint4 v = make_uint4(0, 0, 0, 0);
            if (row < M) v = *(const uint4*)&A[(size_t)row * K + k0 + o * 8];
            *(uint4*)&As[r * LDS_S + o * 8] = v;
        }
        #pragma unroll
        for (int i = 0; i < 2; ++i) {
            int c = t * 2 + i;
            int r = c >> 2, o = c & 3;
            uint4 v = *(const uint4*)&Bt[(size_t)r * K + k0 + o * 8];
            *(uint4*)&Bs[r * LDS_S + o * 8] = v;
        }
        __syncthreads();
        f16x8 af[4], bf[4];
        #pragma unroll
        for (int mt = 0; mt < 4; ++mt)
            af[mt] = *(const f16x8*)&As[(wm * 64 + mt * 16 + l15) * LDS_S + quad * 8];
        #pragma unroll
        for (int nt = 0; nt < 4; ++nt)
            bf[nt] = *(const f16x8*)&Bs[(wn * 64 + nt * 16 + l15) * LDS_S + quad * 8];
        #pragma unroll
        for (int mt = 0; mt < 4; ++mt)
            #pragma unroll
            for (int nt = 0; nt < 4; ++nt)
                acc[mt][nt] = __builtin_amdgcn_mfma_f32_16x16x32_f16(af[mt], bf[nt], acc[mt][nt], 0, 0, 0);
        __syncthreads();
    }

    #pragma unroll
    for (int nt = 0; nt < 4; ++nt) {
        int col = wn * 64 + nt * 16 + l15;
        float b = bias[col];
        #pragma unroll
        for (int mt = 0; mt < 4; ++mt) {
            #pragma unroll
            for (int r = 0; r < 4; ++r) {
                int row = row0 + wm * 64 + mt * 16 + quad * 4 + r;
                if (row < M) {
                    float o = acc[mt][nt][r] + b;
                    if (RELU) o = fmaxf(o, 0.f);
                    C[(size_t)row * 128 + col] = __float2half(o);
                }
            }
        }
    }
}

// ---------------- FUSED: aggregate (+BN+ReLU on source) -> GEMM1 (K=128) ----------------
// Each block stages its own 128-row A-tile by gathering neighbor sums directly
// into LDS, then computes relu(A @ W1^T + b1) via MFMA.
template<bool BN>
__global__ __launch_bounds__(256, 2) void agg_gemm128(
    const __half2* __restrict__ src2, const int* __restrict__ rowptr,
    const unsigned short* __restrict__ col, const float* __restrict__ eps_param, int d,
    const float* __restrict__ s1p, const float* __restrict__ s2p,
    const float* __restrict__ gamma, const float* __restrict__ beta, int dprev,
    const __half* __restrict__ Bt, const float* __restrict__ bias,
    __half* __restrict__ C, int M)
{
    __shared__ __align__(16) __half As[4 * 128 * LDS_S];  // 40 KB
    __shared__ __align__(16) __half Bs[4 * 128 * LDS_S];  // 40 KB

    const int t = threadIdx.x;
    const int w = t >> 6, lane = t & 63;
    const int wm = w >> 1, wn = w & 1;
    const int l15 = lane & 15, quad = lane >> 4;
    const int row0 = blockIdx.x * 128;
    const float e1 = 1.0f + eps_param[d];

    // per-lane BN scale/shift for channels (2*lane, 2*lane+1)
    float2 sc = make_float2(0.f, 0.f), sh = make_float2(0.f, 0.f);
    if (BN) {
        const float inv_n = 1.0f / (float)N_ATOMS;
        int c0 = lane * 2;
        float m0 = s1p[c0] * inv_n;
        float v0 = fmaxf(s2p[c0] * inv_n - m0 * m0, 0.f);
        float m1 = s1p[c0 + 1] * inv_n;
        float v1 = fmaxf(s2p[c0 + 1] * inv_n - m1 * m1, 0.f);
        sc.x = gamma[dprev * 128 + c0]     * rsqrtf(v0 + BN_EPS);
        sc.y = gamma[dprev * 128 + c0 + 1] * rsqrtf(v1 + BN_EPS);
        sh.x = beta[dprev * 128 + c0]     - m0 * sc.x;
        sh.y = beta[dprev * 128 + c0 + 1] - m1 * sc.y;
    }

    // ---- stage B (whole 128x128 weight), coalesced ----
    #pragma unroll
    for (int i = 0; i < 8; ++i) {
        int c = i * 256 + t;
        int r = c >> 4, o = c & 15;
        int kc = o >> 2, oo = o & 3;
        uint4 v = *(const uint4*)&Bt[(size_t)r * 128 + o * 8];
        *(uint4*)&Bs[(kc * 128 + r) * LDS_S + oo * 8] = v;
    }

    // ---- stage A by gathering: wave w handles rows [w*32, w*32+32) ----
    const int kk = lane * 2;
    const int a_kc = kk >> 5, a_off = kk & 31;
    for (int rr = 0; rr < 32; ++rr) {
        int r = w * 32 + rr;
        int row = row0 + r;
        float2 acc = make_float2(0.f, 0.f);
        if (row < M) {
            float2 a = __half22float2(src2[(size_t)row * 64 + lane]);
            if (BN) {
                a.x = fmaxf(a.x * sc.x + sh.x, 0.f);
                a.y = fmaxf(a.y * sc.y + sh.y, 0.f);
            }
            acc.x = a.x * e1;
            acc.y = a.y * e1;
            #pragma unroll
            for (int g = 0; g < NG; ++g) {
                int s = rowptr[g * N_ATOMS + row];
                int e = rowptr[g * N_ATOMS + row + 1];
                for (int i = s; i < e; i += 4) {
                    #pragma unroll
                    for (int u = 0; u < 4; ++u) {
                        int idx = i + u;
                        int c = col[min(idx, e - 1)];
                        float2 f = __half22float2(src2[(size_t)c * 64 + lane]);
                        if (BN) {
                            f.x = fmaxf(f.x * sc.x + sh.x, 0.f);
                            f.y = fmaxf(f.y * sc.y + sh.y, 0.f);
                        }
                        if (idx < e) {
                            acc.x += f.x;
                            acc.y += f.y;
                        }
                    }
                }
            }
        }
        *(__half2*)&As[(size_t)(a_kc * 128 + r) * LDS_S + a_off] = __float22half2_rn(acc);
    }
    __syncthreads();

    // ---- MFMA ----
    f32x4 acc[4][4];
    #pragma unroll
    for (int mt = 0; mt < 4; ++mt)
        #pragma unroll
        for (int nt = 0; nt < 4; ++nt) acc[mt][nt] = (f32x4){0.f, 0.f, 0.f, 0.f};
    #pragma unroll
    for (int kc = 0; kc < 4; ++kc) {
        f16x8 af[4], bf[4];
        #pragma unroll
        for (int mt = 0; mt < 4; ++mt)
            af[mt] = *(const f16x8*)&As[(kc * 128 + wm * 64 + mt * 16 + l15) * LDS_S + quad * 8];
        #pragma unroll
        for (int nt = 0; nt < 4; ++nt)
            bf[nt] = *(const f16x8*)&Bs[(kc * 128 + wn * 64 + nt * 16 + l15) * LDS_S + quad * 8];
        #pragma unroll
        for (int mt = 0; mt < 4; ++mt)
            #pragma unroll
            for (int nt = 0; nt < 4; ++nt)
                acc[mt][nt] = __builtin_amdgcn_mfma_f32_16x16x32_f16(af[mt], bf[nt], acc[mt][nt], 0, 0, 0);
    }

    // ---- epilogue: +bias, ReLU, fp16 store ----
    #pragma unroll
    for (int nt = 0; nt < 4; ++nt) {
        int colc = wn * 64 + nt * 16 + l15;
        float b = bias[colc];
        #pragma unroll
        for (int mt = 0; mt < 4; ++mt) {
            #pragma unroll
            for (int r = 0; r < 4; ++r) {
                int row = row0 + wm * 64 + mt * 16 + quad * 4 + r;
                if (row < M) {
                    float o = fmaxf(acc[mt][nt][r] + b, 0.f);
                    C[(size_t)row * 128 + colc] = __float2half(o);
                }
            }
        }
    }
}

// ---------------- MFMA GEMM, K=128 fixed, with BN stats ----------------
template<bool RELU, bool STATS>
__global__ __launch_bounds__(256, 2) void mfma_gemm128(
    const __half* __restrict__ A, const __half* __restrict__ Bt,
    const float* __restrict__ bias, __half* __restrict__ C,
    int M, float* __restrict__ s1, float* __restrict__ s2)
{
    __shared__ __align__(16) __half As[4 * 128 * LDS_S];
    __shared__ __align__(16) __half Bs[4 * 128 * LDS_S];

    const int t = threadIdx.x;
    const int w = t >> 6, lane = t & 63;
    const int wm = w >> 1, wn = w & 1;
    const int l15 = lane & 15, quad = lane >> 4;
    const int row0 = blockIdx.x * 128;

    f32x4 acc[4][4];
    #pragma unroll
    for (int mt = 0; mt < 4; ++mt)
        #pragma unroll
        for (int nt = 0; nt < 4; ++nt) acc[mt][nt] = (f32x4){0.f, 0.f, 0.f, 0.f};

    #pragma unroll
    for (int i = 0; i < 8; ++i) {
        int c = i * 256 + t;
        int r = c >> 4, o = c & 15;
        int kc = o >> 2, oo = o & 3;
        int row = row0 + r;
        uint4 v = make_uint4(0, 0, 0, 0);
        if (row < M) v = *(const uint4*)&A[(size_t)row * 128 + o * 8];
        *(uint4*)&As[(kc * 128 + r) * LDS_S + oo * 8] = v;
    }
    #pragma unroll
    for (int i = 0; i < 8; ++i) {
        int c = i * 256 + t;
        int r = c >> 4, o = c & 15;
        int kc = o >> 2, oo = o & 3;
        uint4 v = *(const uint4*)&Bt[(size_t)r * 128 + o * 8];
        *(uint4*)&Bs[(kc * 128 + r) * LDS_S + oo * 8] = v;
    }
    __syncthreads();

    #pragma unroll
    for (int kc = 0; kc < 4; ++kc) {
        f16x8 af[4], bf[4];
        #pragma unroll
        for (int mt = 0; mt < 4; ++mt)
            af[mt] = *(const f16x8*)&As[(kc * 128 + wm * 64 + mt * 16 + l15) * LDS_S + quad * 8];
        #pragma unroll
        for (int nt = 0; nt < 4; ++nt)
            bf[nt] = *(const f16x8*)&Bs[(kc * 128 + wn * 64 + nt * 16 + l15) * LDS_S + quad * 8];
        #pragma unroll
        for (int mt = 0; mt < 4; ++mt)
            #pragma unroll
            for (int nt = 0; nt < 4; ++nt)
                acc[mt][nt] = __builtin_amdgcn_mfma_f32_16x16x32_f16(af[mt], bf[nt], acc[mt][nt], 0, 0, 0);
    }

    float ps[4] = {0, 0, 0, 0}, pss[4] = {0, 0, 0, 0};
    #pragma unroll
    for (int nt = 0; nt < 4; ++nt) {
        int col = wn * 64 + nt * 16 + l15;
        float b = bias[col];
        #pragma unroll
        for (int mt = 0; mt < 4; ++mt) {
            #pragma unroll
            for (int r = 0; r < 4; ++r) {
                int row = row0 + wm * 64 + mt * 16 + quad * 4 + r;
                if (row < M) {
                    float o = acc[mt][nt][r] + b;
                    if (STATS) { ps[nt] += o; pss[nt] += o * o; }
                    if (RELU) o = fmaxf(o, 0.f);
                    C[(size_t)row * 128 + col] = __float2half(o);
                }
            }
        }
    }

    if (STATS) {
        float* red1 = (float*)As;
        float* red2 = (float*)Bs;
        int contrib = wm * 4 + quad;
        __syncthreads();
        #pragma unroll
        for (int nt = 0; nt < 4; ++nt) {
            int col = wn * 64 + nt * 16 + l15;
            red1[contrib * 128 + col] = ps[nt];
            red2[contrib * 128 + col] = pss[nt];
        }
        __syncthreads();
        if (t < 128) {
            float s = 0.f, q = 0.f;
            #pragma unroll
            for (int g = 0; g < 8; ++g) {
                s += red1[g * 128 + t];
                q += red2[g * 128 + t];
            }
            atomicAdd(&s1[t], s);
            atomicAdd(&s2[t], q);
        }
    }
}

// ---------------- per-molecule mean pooling with fused BN+ReLU ----------------
__global__ void pool_kernel(const __half* __restrict__ hh, const int* __restrict__ off,
                            const float* __restrict__ s1, const float* __restrict__ s2,
                            const float* __restrict__ gamma, const float* __restrict__ beta,
                            int dprev, float* __restrict__ out)
{
    int m = blockIdx.x;
    int c = threadIdx.x;
    const float inv_n = 1.0f / (float)N_ATOMS;
    float mean = s1[c] * inv_n;
    float var = fmaxf(s2[c] * inv_n - mean * mean, 0.f);
    float sc = gamma[dprev * 128 + c] * rsqrtf(var + BN_EPS);
    float sh = beta[dprev * 128 + c] - mean * sc;
    int s = off[m], e = off[m + 1];
    float acc = 0.f;
    for (int r = s; r < e; ++r) {
        float v = __half2float(hh[(size_t)r * 128 + c]);
        acc += fmaxf(v * sc + sh, 0.f);
    }
    int cnt = e - s;
    out[m * 128 + c] = (cnt > 0) ? acc / (float)cnt : 0.f;
}

// ---------------- launcher ----------------
extern "C" void kernel_launch(void* const* d_in, const int* in_sizes, int n_in,
                              void* d_out, int out_size, void* d_ws, size_t ws_size,
                              hipStream_t stream)
{
    const float* f_atoms   = (const float*)d_in[0];
    const float* W_in      = (const float*)d_in[1];
    const float* b_in      = (const float*)d_in[2];
    const float* W1        = (const float*)d_in[3];
    const float* b1        = (const float*)d_in[4];
    const float* W2        = (const float*)d_in[5];
    const float* b2        = (const float*)d_in[6];
    const float* gamma     = (const float*)d_in[7];
    const float* beta      = (const float*)d_in[8];
    const float* eps_param = (const float*)d_in[9];
    const int*   edge_index= (const int*)d_in[10];
    const int*   seg       = (const int*)d_in[11];
    const int*   src = edge_index;
    const int*   tgt = edge_index + N_EDGES;
    float* out = (float*)d_out;

    char* ws = (char*)d_ws;
    size_t off = 0;
    auto alloc = [&](size_t bytes) -> char* {
        char* p = ws + off;
        off += (bytes + 255) & ~(size_t)255;
        return p;
    };
    __half* xh    = (__half*)alloc((size_t)N_ATOMS * HIDDEN * 2);   // x0 = relu(proj)
    __half* hh    = (__half*)alloc((size_t)N_ATOMS * HIDDEN * 2);   // gemm1 out
    __half* hpre  = (__half*)alloc((size_t)N_ATOMS * HIDDEN * 2);   // gemm2 out (pre-BN h)
    __half* Ah    = (__half*)alloc((size_t)N_ATOMS * K_IN_PAD * 2);
    __half* Wt    = (__half*)alloc((size_t)(128 * K_IN_PAD + 2 * DEPTH * 128 * 128) * 2);
    int*   rowptr = (int*)alloc((NG * N_ATOMS + 1) * 4);
    int*   wcur   = (int*)alloc(NG * N_ATOMS * 4);
    int*   part1  = (int*)alloc(NG * N_ATOMS * 4);
    int*   bsum1  = (int*)alloc(1024 * 4);
    int*   part2  = (int*)alloc(1024 * 4);
    int*   bsum2  = (int*)alloc(256 * 4);
    unsigned short* col = (unsigned short*)alloc((size_t)N_EDGES * 2);
    float* s12    = (float*)alloc(DEPTH * 256 * 4);
    int*   moloff = (int*)alloc((N_MOLS + 1) * 4);

    const __half* Wt_in = Wt;
    const __half* W1t   = Wt + 128 * K_IN_PAD;
    const __half* W2t   = W1t + DEPTH * 128 * 128;

    // ---- grouped CSR build ----
    const int NSC = NG * N_ATOMS;               // 200000
    hipMemsetAsync(wcur, 0, NSC * 4, stream);
    hist_kernel<<<N_EDGES / 256, 256, 0, stream>>>(tgt, N_EDGES, wcur);
    const int NB1 = (NSC + 255) / 256;          // 782
    const int NB2 = (NB1 + 255) / 256;          // 4
    scan_block_kernel<<<NB1, 256, 0, stream>>>(wcur, part1, bsum1, NSC);
    scan_block_kernel<<<NB2, 256, 0, stream>>>(bsum1, part2, bsum2, NB1);
    scan_top_kernel<<<1, 256, 0, stream>>>(bsum2, NB2);
    scan_add2_kernel<<<NB1, 256, 0, stream>>>(part1, part2, bsum2, rowptr, wcur, NSC, N_EDGES);
    fill_csr_kernel<<<N_EDGES / 256, 256, 0, stream>>>(src, tgt, N_EDGES, wcur, col);

    // ---- fused setup ----
    {
        const int NCH = N_ATOMS * (K_IN_PAD / 4);
        const int NW4 = (128 * K_IN_PAD + 2 * DEPTH * 128 * 128) / 4;
        const int TOT = NCH + NW4 + N_MOLS + 1;
        setup_kernel<<<(TOT + 255) / 256, 256, 0, stream>>>(
            f_atoms, W_in, W1, W2, seg, Ah, Wt, s12, moloff);
    }

    // ---- input projection + ReLU -> fp16 x0 ----
    const int GB = (N_ATOMS + 127) / 128;   // 391
    mfma_gemm<true><<<GB, 256, 0, stream>>>(Ah, Wt_in, b_in, xh, N_ATOMS, K_IN_PAD);

    for (int d = 0; d < DEPTH; ++d) {
        float* s1d = s12 + d * 256;
        float* s2d = s1d + 128;
        if (d == 0) {
            agg_gemm128<false><<<GB, 256, 0, stream>>>(
                (const __half2*)xh, rowptr, col, eps_param, d,
                nullptr, nullptr, nullptr, nullptr, 0,
                W1t + (size_t)d * 128 * 128, b1 + d * HIDDEN, hh, N_ATOMS);
        } else {
            float* s1p = s12 + (d - 1) * 256;
            float* s2p = s1p + 128;
            agg_gemm128<true><<<GB, 256, 0, stream>>>(
                (const __half2*)hpre, rowptr, col, eps_param, d,
                s1p, s2p, gamma, beta, d - 1,
                W1t + (size_t)d * 128 * 128, b1 + d * HIDDEN, hh, N_ATOMS);
        }
        mfma_gemm128<false, true><<<GB, 256, 0, stream>>>(
            hh, W2t + (size_t)d * 128 * 128, b2 + d * HIDDEN, hpre,
            N_ATOMS, s1d, s2d);
    }

    pool_kernel<<<N_MOLS, 128, 0, stream>>>(
        hpre, moloff, s12 + (DEPTH - 1) * 256, s12 + (DEPTH - 1) * 256 + 128,
        gamma, beta, DEPTH - 1, out);
}

// Round 6
// 463.876 us; speedup vs baseline: 1.7632x; 1.7632x over previous
//
#include <hip/hip_runtime.h>
#include <hip/hip_fp16.h>

#define N_ATOMS   50000
#define ATOM_FDIM 133
#define HIDDEN    128
#define DEPTH     3
#define N_EDGES   800000
#define N_MOLS    1024
#define BN_EPS    1e-5f
#define K_IN_PAD  160   // 133 padded to 5*32
#define NG        4     // CSR groups (XCD-affine via blockIdx&3)

typedef _Float16 f16x8 __attribute__((ext_vector_type(8)));
typedef float    f32x4 __attribute__((ext_vector_type(4)));

struct __align__(8) half4pack { __half2 a, b; };

// ---------------- histogram (grouped) ----------------
__global__ void hist_kernel(const int* __restrict__ idx, int n, int* __restrict__ cnt) {
    int i = blockIdx.x * blockDim.x + threadIdx.x;
    int g = blockIdx.x & (NG - 1);
    if (i < n) atomicAdd(&cnt[g * N_ATOMS + idx[i]], 1);
}

// ---------------- hierarchical exclusive scan ----------------
__global__ void scan_block_kernel(const int* __restrict__ in, int* __restrict__ out,
                                  int* __restrict__ bsum, int n) {
    __shared__ int buf[256];
    int i = blockIdx.x * 256 + threadIdx.x;
    int v = (i < n) ? in[i] : 0;
    buf[threadIdx.x] = v;
    __syncthreads();
    #pragma unroll
    for (int off = 1; off < 256; off <<= 1) {
        int t = (threadIdx.x >= off) ? buf[threadIdx.x - off] : 0;
        __syncthreads();
        buf[threadIdx.x] += t;
        __syncthreads();
    }
    if (i < n) out[i] = buf[threadIdx.x] - v;
    if (threadIdx.x == 255) bsum[blockIdx.x] = buf[255];
}

__global__ void scan_top_kernel(int* __restrict__ bsum, int nb) {
    __shared__ int buf[256];
    int v = (threadIdx.x < nb) ? bsum[threadIdx.x] : 0;
    buf[threadIdx.x] = v;
    __syncthreads();
    #pragma unroll
    for (int off = 1; off < 256; off <<= 1) {
        int t = (threadIdx.x >= off) ? buf[threadIdx.x - off] : 0;
        __syncthreads();
        buf[threadIdx.x] += t;
        __syncthreads();
    }
    if (threadIdx.x < nb) bsum[threadIdx.x] = buf[threadIdx.x] - v;
}

// rowptr[i] = p1[i] + p2[i/256] + b2[i/65536]; also init wcur
__global__ void scan_add2_kernel(const int* __restrict__ p1, const int* __restrict__ p2,
                                 const int* __restrict__ b2,
                                 int* __restrict__ rowptr, int* __restrict__ wcur,
                                 int n, int total) {
    int i = blockIdx.x * 256 + threadIdx.x;
    if (i < n) {
        int v = p1[i] + p2[i >> 8] + b2[i >> 16];
        rowptr[i] = v;
        wcur[i]   = v;
    }
    if (i == 0) rowptr[n] = total;
}

// ---------------- CSR fill (grouped; col as uint16: src < 65536) ----------------
__global__ void fill_csr_kernel(const int* __restrict__ src, const int* __restrict__ tgt,
                                int n, int* __restrict__ wcur, unsigned short* __restrict__ col) {
    int e = blockIdx.x * blockDim.x + threadIdx.x;
    int g = blockIdx.x & (NG - 1);
    if (e < n) {
        int t = tgt[e];
        int p = atomicAdd(&wcur[g * N_ATOMS + t], 1);
        col[p] = (unsigned short)src[e];
    }
}

// ---------------- fused setup: atoms->fp16(pad), weights->fp16^T, stats zero, mol offsets ----
__global__ void setup_kernel(const float* __restrict__ f,
                             const float* __restrict__ W_in,
                             const float* __restrict__ W1,
                             const float* __restrict__ W2,
                             const int* __restrict__ seg,
                             __half* __restrict__ Ah, __half* __restrict__ Wt,
                             float* __restrict__ stats, int* __restrict__ moloff)
{
    const int NCH = N_ATOMS * (K_IN_PAD / 4);
    const int NW4 = (128 * K_IN_PAD + 2 * DEPTH * 128 * 128) / 4;
    int i = blockIdx.x * 256 + threadIdx.x;
    if (i < NCH) {
        int row = i / (K_IN_PAD / 4);
        int c4  = (i - row * (K_IN_PAD / 4)) * 4;
        float v[4];
        #pragma unroll
        for (int u = 0; u < 4; ++u) {
            int k = c4 + u;
            v[u] = (k < ATOM_FDIM) ? f[(size_t)row * ATOM_FDIM + k] : 0.f;
        }
        half4pack p;
        p.a = __float22half2_rn(make_float2(v[0], v[1]));
        p.b = __float22half2_rn(make_float2(v[2], v[3]));
        *(half4pack*)&Ah[(size_t)row * K_IN_PAD + c4] = p;
        return;
    }
    int j = i - NCH;
    if (j < NW4) {
        float v[4];
        #pragma unroll
        for (int u = 0; u < 4; ++u) {
            int e = j * 4 + u;
            if (e < 128 * K_IN_PAD) {
                int n = e / K_IN_PAD, k = e - n * K_IN_PAD;
                v[u] = (k < ATOM_FDIM) ? W_in[(size_t)k * 128 + n] : 0.f;
            } else if (e < 128 * K_IN_PAD + DEPTH * 128 * 128) {
                int q = e - 128 * K_IN_PAD;
                int d = q >> 14, r = q & 16383;
                int n = r >> 7, k = r & 127;
                v[u] = W1[((size_t)d * 128 + k) * 128 + n];
            } else {
                int q = e - 128 * K_IN_PAD - DEPTH * 128 * 128;
                int d = q >> 14, r = q & 16383;
                int n = r >> 7, k = r & 127;
                v[u] = W2[((size_t)d * 128 + k) * 128 + n];
            }
        }
        half4pack p;
        p.a = __float22half2_rn(make_float2(v[0], v[1]));
        p.b = __float22half2_rn(make_float2(v[2], v[3]));
        *(half4pack*)&Wt[j * 4] = p;
        return;
    }
    int m = j - NW4;
    if (m < DEPTH * 256) stats[m] = 0.f;
    if (m <= N_MOLS) {
        int lo = 0, hi = N_ATOMS;
        while (lo < hi) {
            int mid = (lo + hi) >> 1;
            if (seg[mid] < m) lo = mid + 1; else hi = mid;
        }
        moloff[m] = lo;
    }
}

#define LDS_S 40   // padded stride (halves) per 32-half k-chunk row

// ---------------- MFMA GEMM, K variable (input projection) ----------------
template<bool RELU>
__global__ __launch_bounds__(256, 2) void mfma_gemm(
    const __half* __restrict__ A, const __half* __restrict__ Bt,
    const float* __restrict__ bias, __half* __restrict__ C, int M, int K)
{
    __shared__ __align__(16) __half As[128 * LDS_S];
    __shared__ __align__(16) __half Bs[128 * LDS_S];

    const int t = threadIdx.x;
    const int w = t >> 6, lane = t & 63;
    const int wm = w >> 1, wn = w & 1;
    const int l15 = lane & 15, quad = lane >> 4;
    const int row0 = blockIdx.x * 128;

    f32x4 acc[4][4];
    #pragma unroll
    for (int mt = 0; mt < 4; ++mt)
        #pragma unroll
        for (int nt = 0; nt < 4; ++nt) acc[mt][nt] = (f32x4){0.f, 0.f, 0.f, 0.f};

    for (int k0 = 0; k0 < K; k0 += 32) {
        #pragma unroll
        for (int i = 0; i < 2; ++i) {
            int c = t * 2 + i;
            int r = c >> 2, o = c & 3;
            int row = row0 + r;
            uint4 v = make_uint4(0, 0, 0, 0);
            if (row < M) v = *(const uint4*)&A[(size_t)row * K + k0 + o * 8];
            *(uint4*)&As[r * LDS_S + o * 8] = v;
        }
        #pragma unroll
        for (int i = 0; i < 2; ++i) {
            int c = t * 2 + i;
            int r = c >> 2, o = c & 3;
            uint4 v = *(const uint4*)&Bt[(size_t)r * K + k0 + o * 8];
            *(uint4*)&Bs[r * LDS_S + o * 8] = v;
        }
        __syncthreads();
        f16x8 af[4], bf[4];
        #pragma unroll
        for (int mt = 0; mt < 4; ++mt)
            af[mt] = *(const f16x8*)&As[(wm * 64 + mt * 16 + l15) * LDS_S + quad * 8];
        #pragma unroll
        for (int nt = 0; nt < 4; ++nt)
            bf[nt] = *(const f16x8*)&Bs[(wn * 64 + nt * 16 + l15) * LDS_S + quad * 8];
        #pragma unroll
        for (int mt = 0; mt < 4; ++mt)
            #pragma unroll
            for (int nt = 0; nt < 4; ++nt)
                acc[mt][nt] = __builtin_amdgcn_mfma_f32_16x16x32_f16(af[mt], bf[nt], acc[mt][nt], 0, 0, 0);
        __syncthreads();
    }

    #pragma unroll
    for (int nt = 0; nt < 4; ++nt) {
        int col = wn * 64 + nt * 16 + l15;
        float b = bias[col];
        #pragma unroll
        for (int mt = 0; mt < 4; ++mt) {
            #pragma unroll
            for (int r = 0; r < 4; ++r) {
                int row = row0 + wm * 64 + mt * 16 + quad * 4 + r;
                if (row < M) {
                    float o = acc[mt][nt][r] + b;
                    if (RELU) o = fmaxf(o, 0.f);
                    C[(size_t)row * 128 + col] = __float2half(o);
                }
            }
        }
    }
}

// ---------------- MFMA GEMM, K=128 fixed, with BN stats ----------------
template<bool RELU, bool STATS>
__global__ __launch_bounds__(256, 2) void mfma_gemm128(
    const __half* __restrict__ A, const __half* __restrict__ Bt,
    const float* __restrict__ bias, __half* __restrict__ C,
    int M, float* __restrict__ s1, float* __restrict__ s2)
{
    __shared__ __align__(16) __half As[4 * 128 * LDS_S];
    __shared__ __align__(16) __half Bs[4 * 128 * LDS_S];

    const int t = threadIdx.x;
    const int w = t >> 6, lane = t & 63;
    const int wm = w >> 1, wn = w & 1;
    const int l15 = lane & 15, quad = lane >> 4;
    const int row0 = blockIdx.x * 128;

    f32x4 acc[4][4];
    #pragma unroll
    for (int mt = 0; mt < 4; ++mt)
        #pragma unroll
        for (int nt = 0; nt < 4; ++nt) acc[mt][nt] = (f32x4){0.f, 0.f, 0.f, 0.f};

    #pragma unroll
    for (int i = 0; i < 8; ++i) {
        int c = i * 256 + t;
        int r = c >> 4, o = c & 15;
        int kc = o >> 2, oo = o & 3;
        int row = row0 + r;
        uint4 v = make_uint4(0, 0, 0, 0);
        if (row < M) v = *(const uint4*)&A[(size_t)row * 128 + o * 8];
        *(uint4*)&As[(kc * 128 + r) * LDS_S + oo * 8] = v;
    }
    #pragma unroll
    for (int i = 0; i < 8; ++i) {
        int c = i * 256 + t;
        int r = c >> 4, o = c & 15;
        int kc = o >> 2, oo = o & 3;
        uint4 v = *(const uint4*)&Bt[(size_t)r * 128 + o * 8];
        *(uint4*)&Bs[(kc * 128 + r) * LDS_S + oo * 8] = v;
    }
    __syncthreads();

    #pragma unroll
    for (int kc = 0; kc < 4; ++kc) {
        f16x8 af[4], bf[4];
        #pragma unroll
        for (int mt = 0; mt < 4; ++mt)
            af[mt] = *(const f16x8*)&As[(kc * 128 + wm * 64 + mt * 16 + l15) * LDS_S + quad * 8];
        #pragma unroll
        for (int nt = 0; nt < 4; ++nt)
            bf[nt] = *(const f16x8*)&Bs[(kc * 128 + wn * 64 + nt * 16 + l15) * LDS_S + quad * 8];
        #pragma unroll
        for (int mt = 0; mt < 4; ++mt)
            #pragma unroll
            for (int nt = 0; nt < 4; ++nt)
                acc[mt][nt] = __builtin_amdgcn_mfma_f32_16x16x32_f16(af[mt], bf[nt], acc[mt][nt], 0, 0, 0);
    }

    float ps[4] = {0, 0, 0, 0}, pss[4] = {0, 0, 0, 0};
    #pragma unroll
    for (int nt = 0; nt < 4; ++nt) {
        int col = wn * 64 + nt * 16 + l15;
        float b = bias[col];
        #pragma unroll
        for (int mt = 0; mt < 4; ++mt) {
            #pragma unroll
            for (int r = 0; r < 4; ++r) {
                int row = row0 + wm * 64 + mt * 16 + quad * 4 + r;
                if (row < M) {
                    float o = acc[mt][nt][r] + b;
                    if (STATS) { ps[nt] += o; pss[nt] += o * o; }
                    if (RELU) o = fmaxf(o, 0.f);
                    C[(size_t)row * 128 + col] = __float2half(o);
                }
            }
        }
    }

    if (STATS) {
        float* red1 = (float*)As;
        float* red2 = (float*)Bs;
        int contrib = wm * 4 + quad;
        __syncthreads();
        #pragma unroll
        for (int nt = 0; nt < 4; ++nt) {
            int col = wn * 64 + nt * 16 + l15;
            red1[contrib * 128 + col] = ps[nt];
            red2[contrib * 128 + col] = pss[nt];
        }
        __syncthreads();
        if (t < 128) {
            float s = 0.f, q = 0.f;
            #pragma unroll
            for (int g = 0; g < 8; ++g) {
                s += red1[g * 128 + t];
                q += red2[g * 128 + t];
            }
            atomicAdd(&s1[t], s);
            atomicAdd(&s2[t], q);
        }
    }
}

// ---------------- aggregate (wave-per-atom, 4 group segments), fused BN+ReLU on source ----
template<bool BN>
__global__ __launch_bounds__(256) void aggregate_kernel(
    const __half2* __restrict__ xh2, const int* __restrict__ rowptr,
    const unsigned short* __restrict__ col, const float* __restrict__ eps_param, int d,
    const float* __restrict__ s1, const float* __restrict__ s2,
    const float* __restrict__ gamma, const float* __restrict__ beta, int dprev,
    __half2* __restrict__ aggh2)
{
    int gw = (blockIdx.x * 256 + threadIdx.x) >> 6;   // one wave per atom
    int lane = threadIdx.x & 63;
    float e1 = 1.0f + eps_param[d];

    float2 sc = make_float2(0.f, 0.f), sh = make_float2(0.f, 0.f);
    if (BN) {
        const float inv_n = 1.0f / (float)N_ATOMS;
        int c0 = lane * 2;
        float m0 = s1[c0] * inv_n;
        float v0 = fmaxf(s2[c0] * inv_n - m0 * m0, 0.f);
        float m1 = s1[c0 + 1] * inv_n;
        float v1 = fmaxf(s2[c0 + 1] * inv_n - m1 * m1, 0.f);
        sc.x = gamma[dprev * 128 + c0]     * rsqrtf(v0 + BN_EPS);
        sc.y = gamma[dprev * 128 + c0 + 1] * rsqrtf(v1 + BN_EPS);
        sh.x = beta[dprev * 128 + c0]     - m0 * sc.x;
        sh.y = beta[dprev * 128 + c0 + 1] - m1 * sc.y;
    }

    // preload all group segment bounds (wave-uniform scalar loads)
    int ss[NG], ee[NG];
    #pragma unroll
    for (int g = 0; g < NG; ++g) {
        ss[g] = rowptr[g * N_ATOMS + gw];
        ee[g] = rowptr[g * N_ATOMS + gw + 1];
    }

    float2 a = __half22float2(xh2[(size_t)gw * 64 + lane]);
    if (BN) {
        a.x = fmaxf(a.x * sc.x + sh.x, 0.f);
        a.y = fmaxf(a.y * sc.y + sh.y, 0.f);
    }
    float2 acc;
    acc.x = a.x * e1;
    acc.y = a.y * e1;

    #pragma unroll
    for (int g = 0; g < NG; ++g) {
        int s = ss[g], e = ee[g];
        for (int i = s; i < e; i += 4) {
            #pragma unroll
            for (int u = 0; u < 4; ++u) {
                int idx = i + u;
                int c = col[min(idx, e - 1)];
                float2 f = __half22float2(xh2[(size_t)c * 64 + lane]);
                if (BN) {
                    f.x = fmaxf(f.x * sc.x + sh.x, 0.f);
                    f.y = fmaxf(f.y * sc.y + sh.y, 0.f);
                }
                if (idx < e) {
                    acc.x += f.x;
                    acc.y += f.y;
                }
            }
        }
    }
    aggh2[(size_t)gw * 64 + lane] = __float22half2_rn(acc);
}

// ---------------- per-molecule mean pooling with fused BN+ReLU ----------------
__global__ void pool_kernel(const __half* __restrict__ hh, const int* __restrict__ off,
                            const float* __restrict__ s1, const float* __restrict__ s2,
                            const float* __restrict__ gamma, const float* __restrict__ beta,
                            int dprev, float* __restrict__ out)
{
    int m = blockIdx.x;
    int c = threadIdx.x;
    const float inv_n = 1.0f / (float)N_ATOMS;
    float mean = s1[c] * inv_n;
    float var = fmaxf(s2[c] * inv_n - mean * mean, 0.f);
    float sc = gamma[dprev * 128 + c] * rsqrtf(var + BN_EPS);
    float sh = beta[dprev * 128 + c] - mean * sc;
    int s = off[m], e = off[m + 1];
    float acc = 0.f;
    for (int r = s; r < e; ++r) {
        float v = __half2float(hh[(size_t)r * 128 + c]);
        acc += fmaxf(v * sc + sh, 0.f);
    }
    int cnt = e - s;
    out[m * 128 + c] = (cnt > 0) ? acc / (float)cnt : 0.f;
}

// ---------------- launcher ----------------
extern "C" void kernel_launch(void* const* d_in, const int* in_sizes, int n_in,
                              void* d_out, int out_size, void* d_ws, size_t ws_size,
                              hipStream_t stream)
{
    const float* f_atoms   = (const float*)d_in[0];
    const float* W_in      = (const float*)d_in[1];
    const float* b_in      = (const float*)d_in[2];
    const float* W1        = (const float*)d_in[3];
    const float* b1        = (const float*)d_in[4];
    const float* W2        = (const float*)d_in[5];
    const float* b2        = (const float*)d_in[6];
    const float* gamma     = (const float*)d_in[7];
    const float* beta      = (const float*)d_in[8];
    const float* eps_param = (const float*)d_in[9];
    const int*   edge_index= (const int*)d_in[10];
    const int*   seg       = (const int*)d_in[11];
    const int*   src = edge_index;
    const int*   tgt = edge_index + N_EDGES;
    float* out = (float*)d_out;

    char* ws = (char*)d_ws;
    size_t off = 0;
    auto alloc = [&](size_t bytes) -> char* {
        char* p = ws + off;
        off += (bytes + 255) & ~(size_t)255;
        return p;
    };
    __half* xh    = (__half*)alloc((size_t)N_ATOMS * HIDDEN * 2);   // x0 = relu(proj)
    __half* aggh  = (__half*)alloc((size_t)N_ATOMS * HIDDEN * 2);   // aggregate out
    __half* hh    = (__half*)alloc((size_t)N_ATOMS * HIDDEN * 2);   // gemm1 out
    __half* hpre  = (__half*)alloc((size_t)N_ATOMS * HIDDEN * 2);   // gemm2 out (pre-BN h)
    __half* Ah    = (__half*)alloc((size_t)N_ATOMS * K_IN_PAD * 2);
    __half* Wt    = (__half*)alloc((size_t)(128 * K_IN_PAD + 2 * DEPTH * 128 * 128) * 2);
    int*   rowptr = (int*)alloc((NG * N_ATOMS + 1) * 4);
    int*   wcur   = (int*)alloc(NG * N_ATOMS * 4);
    int*   part1  = (int*)alloc(NG * N_ATOMS * 4);
    int*   bsum1  = (int*)alloc(1024 * 4);
    int*   part2  = (int*)alloc(1024 * 4);
    int*   bsum2  = (int*)alloc(256 * 4);
    unsigned short* col = (unsigned short*)alloc((size_t)N_EDGES * 2);
    float* s12    = (float*)alloc(DEPTH * 256 * 4);
    int*   moloff = (int*)alloc((N_MOLS + 1) * 4);

    const __half* Wt_in = Wt;
    const __half* W1t   = Wt + 128 * K_IN_PAD;
    const __half* W2t   = W1t + DEPTH * 128 * 128;

    // ---- grouped CSR build ----
    const int NSC = NG * N_ATOMS;               // 200000
    hipMemsetAsync(wcur, 0, NSC * 4, stream);
    hist_kernel<<<N_EDGES / 256, 256, 0, stream>>>(tgt, N_EDGES, wcur);
    const int NB1 = (NSC + 255) / 256;          // 782
    const int NB2 = (NB1 + 255) / 256;          // 4
    scan_block_kernel<<<NB1, 256, 0, stream>>>(wcur, part1, bsum1, NSC);
    scan_block_kernel<<<NB2, 256, 0, stream>>>(bsum1, part2, bsum2, NB1);
    scan_top_kernel<<<1, 256, 0, stream>>>(bsum2, NB2);
    scan_add2_kernel<<<NB1, 256, 0, stream>>>(part1, part2, bsum2, rowptr, wcur, NSC, N_EDGES);
    fill_csr_kernel<<<N_EDGES / 256, 256, 0, stream>>>(src, tgt, N_EDGES, wcur, col);

    // ---- fused setup ----
    {
        const int NCH = N_ATOMS * (K_IN_PAD / 4);
        const int NW4 = (128 * K_IN_PAD + 2 * DEPTH * 128 * 128) / 4;
        const int TOT = NCH + NW4 + N_MOLS + 1;
        setup_kernel<<<(TOT + 255) / 256, 256, 0, stream>>>(
            f_atoms, W_in, W1, W2, seg, Ah, Wt, s12, moloff);
    }

    // ---- input projection + ReLU -> fp16 x0 ----
    const int GB = (N_ATOMS + 127) / 128;   // 391
    mfma_gemm<true><<<GB, 256, 0, stream>>>(Ah, Wt_in, b_in, xh, N_ATOMS, K_IN_PAD);

    for (int d = 0; d < DEPTH; ++d) {
        float* s1d = s12 + d * 256;
        float* s2d = s1d + 128;
        if (d == 0) {
            aggregate_kernel<false><<<N_ATOMS / 4, 256, 0, stream>>>(
                (const __half2*)xh, rowptr, col, eps_param, d,
                nullptr, nullptr, nullptr, nullptr, 0, (__half2*)aggh);
        } else {
            float* s1p = s12 + (d - 1) * 256;
            float* s2p = s1p + 128;
            aggregate_kernel<true><<<N_ATOMS / 4, 256, 0, stream>>>(
                (const __half2*)hpre, rowptr, col, eps_param, d,
                s1p, s2p, gamma, beta, d - 1, (__half2*)aggh);
        }
        mfma_gemm128<true, false><<<GB, 256, 0, stream>>>(
            aggh, W1t + (size_t)d * 128 * 128, b1 + d * HIDDEN, hh,
            N_ATOMS, nullptr, nullptr);
        mfma_gemm128<false, true><<<GB, 256, 0, stream>>>(
            hh, W2t + (size_t)d * 128 * 128, b2 + d * HIDDEN, hpre,
            N_ATOMS, s1d, s2d);
    }

    pool_kernel<<<N_MOLS, 128, 0, stream>>>(
        hpre, moloff, s12 + (DEPTH - 1) * 256, s12 + (DEPTH - 1) * 256 + 128,
        gamma, beta, DEPTH - 1, out);
}

// Round 7
// 391.914 us; speedup vs baseline: 2.0869x; 1.1836x over previous
//
#include <hip/hip_runtime.h>
#include <hip/hip_fp16.h>

#define N_ATOMS   50000
#define ATOM_FDIM 133
#define HIDDEN    128
#define DEPTH     3
#define N_EDGES   800000
#define N_MOLS    1024
#define BN_EPS    1e-5f
#define K_IN_PAD  160   // 133 padded to 5*32

typedef _Float16 f16x8 __attribute__((ext_vector_type(8)));
typedef float    f32x4 __attribute__((ext_vector_type(4)));

struct __align__(8) half4pack { __half2 a, b; };

// ---------------- histogram ----------------
__global__ void hist_kernel(const int* __restrict__ idx, int n, int* __restrict__ cnt) {
    int i = blockIdx.x * blockDim.x + threadIdx.x;
    if (i < n) atomicAdd(&cnt[idx[i]], 1);
}

// ---------------- hierarchical exclusive scan ----------------
__global__ void scan_block_kernel(const int* __restrict__ in, int* __restrict__ out,
                                  int* __restrict__ bsum, int n) {
    __shared__ int buf[256];
    int i = blockIdx.x * 256 + threadIdx.x;
    int v = (i < n) ? in[i] : 0;
    buf[threadIdx.x] = v;
    __syncthreads();
    #pragma unroll
    for (int off = 1; off < 256; off <<= 1) {
        int t = (threadIdx.x >= off) ? buf[threadIdx.x - off] : 0;
        __syncthreads();
        buf[threadIdx.x] += t;
        __syncthreads();
    }
    if (i < n) out[i] = buf[threadIdx.x] - v;
    if (threadIdx.x == 255) bsum[blockIdx.x] = buf[255];
}

__global__ void scan_top_kernel(int* __restrict__ bsum, int nb) {
    __shared__ int buf[256];
    int v = (threadIdx.x < nb) ? bsum[threadIdx.x] : 0;
    buf[threadIdx.x] = v;
    __syncthreads();
    #pragma unroll
    for (int off = 1; off < 256; off <<= 1) {
        int t = (threadIdx.x >= off) ? buf[threadIdx.x - off] : 0;
        __syncthreads();
        buf[threadIdx.x] += t;
        __syncthreads();
    }
    if (threadIdx.x < nb) bsum[threadIdx.x] = buf[threadIdx.x] - v;
}

__global__ void scan_add_kernel(const int* __restrict__ partial, const int* __restrict__ bsum,
                                int* __restrict__ rowptr, int* __restrict__ wcur,
                                int n, int total) {
    int i = blockIdx.x * 256 + threadIdx.x;
    if (i < n) {
        int v = partial[i] + bsum[blockIdx.x];
        rowptr[i] = v;
        wcur[i]   = v;
    }
    if (i == 0) rowptr[n] = total;
}

// ---------------- CSR fill (col as uint16: src < 65536) ----------------
__global__ void fill_csr_kernel(const int* __restrict__ src, const int* __restrict__ tgt,
                                int n, int* __restrict__ wcur, unsigned short* __restrict__ col) {
    int e = blockIdx.x * blockDim.x + threadIdx.x;
    if (e < n) {
        int t = tgt[e];
        int p = atomicAdd(&wcur[t], 1);
        col[p] = (unsigned short)src[e];
    }
}

// ---------------- fused setup: atoms->fp16(pad), weights->fp16^T, stats zero, mol offsets ----
__global__ void setup_kernel(const float* __restrict__ f,
                             const float* __restrict__ W_in,
                             const float* __restrict__ W1,
                             const float* __restrict__ W2,
                             const int* __restrict__ seg,
                             __half* __restrict__ Ah, __half* __restrict__ Wt,
                             float* __restrict__ stats, int* __restrict__ moloff)
{
    const int NCH = N_ATOMS * (K_IN_PAD / 4);
    const int NW4 = (128 * K_IN_PAD + 2 * DEPTH * 128 * 128) / 4;
    int i = blockIdx.x * 256 + threadIdx.x;
    if (i < NCH) {
        int row = i / (K_IN_PAD / 4);
        int c4  = (i - row * (K_IN_PAD / 4)) * 4;
        float v[4];
        #pragma unroll
        for (int u = 0; u < 4; ++u) {
            int k = c4 + u;
            v[u] = (k < ATOM_FDIM) ? f[(size_t)row * ATOM_FDIM + k] : 0.f;
        }
        half4pack p;
        p.a = __float22half2_rn(make_float2(v[0], v[1]));
        p.b = __float22half2_rn(make_float2(v[2], v[3]));
        *(half4pack*)&Ah[(size_t)row * K_IN_PAD + c4] = p;
        return;
    }
    int j = i - NCH;
    if (j < NW4) {
        float v[4];
        #pragma unroll
        for (int u = 0; u < 4; ++u) {
            int e = j * 4 + u;
            if (e < 128 * K_IN_PAD) {
                int n = e / K_IN_PAD, k = e - n * K_IN_PAD;
                v[u] = (k < ATOM_FDIM) ? W_in[(size_t)k * 128 + n] : 0.f;
            } else if (e < 128 * K_IN_PAD + DEPTH * 128 * 128) {
                int q = e - 128 * K_IN_PAD;
                int d = q >> 14, r = q & 16383;
                int n = r >> 7, k = r & 127;
                v[u] = W1[((size_t)d * 128 + k) * 128 + n];
            } else {
                int q = e - 128 * K_IN_PAD - DEPTH * 128 * 128;
                int d = q >> 14, r = q & 16383;
                int n = r >> 7, k = r & 127;
                v[u] = W2[((size_t)d * 128 + k) * 128 + n];
            }
        }
        half4pack p;
        p.a = __float22half2_rn(make_float2(v[0], v[1]));
        p.b = __float22half2_rn(make_float2(v[2], v[3]));
        *(half4pack*)&Wt[j * 4] = p;
        return;
    }
    int m = j - NW4;
    if (m < DEPTH * 256) stats[m] = 0.f;
    if (m <= N_MOLS) {
        int lo = 0, hi = N_ATOMS;
        while (lo < hi) {
            int mid = (lo + hi) >> 1;
            if (seg[mid] < m) lo = mid + 1; else hi = mid;
        }
        moloff[m] = lo;
    }
}

#define LDS_S 40   // padded stride (halves) per 32-half k-chunk row

// ---------------- MFMA GEMM, K variable (input projection) ----------------
template<bool RELU>
__global__ __launch_bounds__(256, 2) void mfma_gemm(
    const __half* __restrict__ A, const __half* __restrict__ Bt,
    const float* __restrict__ bias, __half* __restrict__ C, int M, int K)
{
    __shared__ __align__(16) __half As[128 * LDS_S];
    __shared__ __align__(16) __half Bs[128 * LDS_S];

    const int t = threadIdx.x;
    const int w = t >> 6, lane = t & 63;
    const int wm = w >> 1, wn = w & 1;
    const int l15 = lane & 15, quad = lane >> 4;
    const int row0 = blockIdx.x * 128;

    f32x4 acc[4][4];
    #pragma unroll
    for (int mt = 0; mt < 4; ++mt)
        #pragma unroll
        for (int nt = 0; nt < 4; ++nt) acc[mt][nt] = (f32x4){0.f, 0.f, 0.f, 0.f};

    for (int k0 = 0; k0 < K; k0 += 32) {
        #pragma unroll
        for (int i = 0; i < 2; ++i) {
            int c = t * 2 + i;
            int r = c >> 2, o = c & 3;
            int row = row0 + r;
            uint4 v = make_uint4(0, 0, 0, 0);
            if (row < M) v = *(const uint4*)&A[(size_t)row * K + k0 + o * 8];
            *(uint4*)&As[r * LDS_S + o * 8] = v;
        }
        #pragma unroll
        for (int i = 0; i < 2; ++i) {
            int c = t * 2 + i;
            int r = c >> 2, o = c & 3;
            uint4 v = *(const uint4*)&Bt[(size_t)r * K + k0 + o * 8];
            *(uint4*)&Bs[r * LDS_S + o * 8] = v;
        }
        __syncthreads();
        f16x8 af[4], bf[4];
        #pragma unroll
        for (int mt = 0; mt < 4; ++mt)
            af[mt] = *(const f16x8*)&As[(wm * 64 + mt * 16 + l15) * LDS_S + quad * 8];
        #pragma unroll
        for (int nt = 0; nt < 4; ++nt)
            bf[nt] = *(const f16x8*)&Bs[(wn * 64 + nt * 16 + l15) * LDS_S + quad * 8];
        #pragma unroll
        for (int mt = 0; mt < 4; ++mt)
            #pragma unroll
            for (int nt = 0; nt < 4; ++nt)
                acc[mt][nt] = __builtin_amdgcn_mfma_f32_16x16x32_f16(af[mt], bf[nt], acc[mt][nt], 0, 0, 0);
        __syncthreads();
    }

    #pragma unroll
    for (int nt = 0; nt < 4; ++nt) {
        int col = wn * 64 + nt * 16 + l15;
        float b = bias[col];
        #pragma unroll
        for (int mt = 0; mt < 4; ++mt) {
            #pragma unroll
            for (int r = 0; r < 4; ++r) {
                int row = row0 + wm * 64 + mt * 16 + quad * 4 + r;
                if (row < M) {
                    float o = acc[mt][nt][r] + b;
                    if (RELU) o = fmaxf(o, 0.f);
                    C[(size_t)row * 128 + col] = __float2half(o);
                }
            }
        }
    }
}

// ---------------- FUSED MLP: hpre = relu(agg@W1+b1)@W2+b2, + BN stats ----------------
// Both GEMMs are row-local to the block's 128 rows: compute h in-register,
// route through LDS (A-layout), restage W2 over the B-tile, second MFMA.
__global__ __launch_bounds__(256, 2) void mlp_fused(
    const __half* __restrict__ A, const __half* __restrict__ B1t,
    const __half* __restrict__ B2t,
    const float* __restrict__ bias1, const float* __restrict__ bias2,
    __half* __restrict__ C, int M,
    float* __restrict__ s1, float* __restrict__ s2)
{
    __shared__ __align__(16) __half As[4 * 128 * LDS_S];  // 40 KB
    __shared__ __align__(16) __half Bs[4 * 128 * LDS_S];  // 40 KB

    const int t = threadIdx.x;
    const int w = t >> 6, lane = t & 63;
    const int wm = w >> 1, wn = w & 1;
    const int l15 = lane & 15, quad = lane >> 4;
    const int row0 = blockIdx.x * 128;

    f32x4 acc[4][4];
    #pragma unroll
    for (int mt = 0; mt < 4; ++mt)
        #pragma unroll
        for (int nt = 0; nt < 4; ++nt) acc[mt][nt] = (f32x4){0.f, 0.f, 0.f, 0.f};

    // ---- stage A (agg) + B (W1) ----
    #pragma unroll
    for (int i = 0; i < 8; ++i) {
        int c = i * 256 + t;
        int r = c >> 4, o = c & 15;
        int kc = o >> 2, oo = o & 3;
        int row = row0 + r;
        uint4 v = make_uint4(0, 0, 0, 0);
        if (row < M) v = *(const uint4*)&A[(size_t)row * 128 + o * 8];
        *(uint4*)&As[(kc * 128 + r) * LDS_S + oo * 8] = v;
    }
    #pragma unroll
    for (int i = 0; i < 8; ++i) {
        int c = i * 256 + t;
        int r = c >> 4, o = c & 15;
        int kc = o >> 2, oo = o & 3;
        uint4 v = *(const uint4*)&B1t[(size_t)r * 128 + o * 8];
        *(uint4*)&Bs[(kc * 128 + r) * LDS_S + oo * 8] = v;
    }
    __syncthreads();

    // ---- GEMM1 ----
    #pragma unroll
    for (int kc = 0; kc < 4; ++kc) {
        f16x8 af[4], bf[4];
        #pragma unroll
        for (int mt = 0; mt < 4; ++mt)
            af[mt] = *(const f16x8*)&As[(kc * 128 + wm * 64 + mt * 16 + l15) * LDS_S + quad * 8];
        #pragma unroll
        for (int nt = 0; nt < 4; ++nt)
            bf[nt] = *(const f16x8*)&Bs[(kc * 128 + wn * 64 + nt * 16 + l15) * LDS_S + quad * 8];
        #pragma unroll
        for (int mt = 0; mt < 4; ++mt)
            #pragma unroll
            for (int nt = 0; nt < 4; ++nt)
                acc[mt][nt] = __builtin_amdgcn_mfma_f32_16x16x32_f16(af[mt], bf[nt], acc[mt][nt], 0, 0, 0);
    }
    __syncthreads();   // all As/Bs reads done before overwrite

    // ---- h = relu(acc + b1) -> As (A-layout); restage Bs with W2 ----
    #pragma unroll
    for (int nt = 0; nt < 4; ++nt) {
        int k = wn * 64 + nt * 16 + l15;
        float b = bias1[k];
        int kc = k >> 5, ko = k & 31;
        #pragma unroll
        for (int mt = 0; mt < 4; ++mt) {
            #pragma unroll
            for (int r = 0; r < 4; ++r) {
                int rl = wm * 64 + mt * 16 + quad * 4 + r;
                float h = fmaxf(acc[mt][nt][r] + b, 0.f);
                As[(kc * 128 + rl) * LDS_S + ko] = __float2half(h);
            }
        }
    }
    #pragma unroll
    for (int i = 0; i < 8; ++i) {
        int c = i * 256 + t;
        int r = c >> 4, o = c & 15;
        int kc = o >> 2, oo = o & 3;
        uint4 v = *(const uint4*)&B2t[(size_t)r * 128 + o * 8];
        *(uint4*)&Bs[(kc * 128 + r) * LDS_S + oo * 8] = v;
    }
    __syncthreads();

    // ---- GEMM2 ----
    #pragma unroll
    for (int mt = 0; mt < 4; ++mt)
        #pragma unroll
        for (int nt = 0; nt < 4; ++nt) acc[mt][nt] = (f32x4){0.f, 0.f, 0.f, 0.f};
    #pragma unroll
    for (int kc = 0; kc < 4; ++kc) {
        f16x8 af[4], bf[4];
        #pragma unroll
        for (int mt = 0; mt < 4; ++mt)
            af[mt] = *(const f16x8*)&As[(kc * 128 + wm * 64 + mt * 16 + l15) * LDS_S + quad * 8];
        #pragma unroll
        for (int nt = 0; nt < 4; ++nt)
            bf[nt] = *(const f16x8*)&Bs[(kc * 128 + wn * 64 + nt * 16 + l15) * LDS_S + quad * 8];
        #pragma unroll
        for (int mt = 0; mt < 4; ++mt)
            #pragma unroll
            for (int nt = 0; nt < 4; ++nt)
                acc[mt][nt] = __builtin_amdgcn_mfma_f32_16x16x32_f16(af[mt], bf[nt], acc[mt][nt], 0, 0, 0);
    }

    // ---- epilogue: +b2, BN stats (pre-activation), fp16 store ----
    float ps[4] = {0, 0, 0, 0}, pss[4] = {0, 0, 0, 0};
    #pragma unroll
    for (int nt = 0; nt < 4; ++nt) {
        int col = wn * 64 + nt * 16 + l15;
        float b = bias2[col];
        #pragma unroll
        for (int mt = 0; mt < 4; ++mt) {
            #pragma unroll
            for (int r = 0; r < 4; ++r) {
                int row = row0 + wm * 64 + mt * 16 + quad * 4 + r;
                if (row < M) {
                    float o = acc[mt][nt][r] + b;
                    ps[nt] += o;
                    pss[nt] += o * o;
                    C[(size_t)row * 128 + col] = __float2half(o);
                }
            }
        }
    }

    float* red1 = (float*)As;
    float* red2 = (float*)Bs;
    int contrib = wm * 4 + quad;
    __syncthreads();
    #pragma unroll
    for (int nt = 0; nt < 4; ++nt) {
        int col = wn * 64 + nt * 16 + l15;
        red1[contrib * 128 + col] = ps[nt];
        red2[contrib * 128 + col] = pss[nt];
    }
    __syncthreads();
    if (t < 128) {
        float s = 0.f, q = 0.f;
        #pragma unroll
        for (int g = 0; g < 8; ++g) {
            s += red1[g * 128 + t];
            q += red2[g * 128 + t];
        }
        atomicAdd(&s1[t], s);
        atomicAdd(&s2[t], q);
    }
}

// ---------------- aggregate (wave-per-atom), fused BN+ReLU on source ----------------
template<bool BN>
__global__ __launch_bounds__(256) void aggregate_kernel(
    const __half2* __restrict__ xh2, const int* __restrict__ rowptr,
    const unsigned short* __restrict__ col, const float* __restrict__ eps_param, int d,
    const float* __restrict__ s1, const float* __restrict__ s2,
    const float* __restrict__ gamma, const float* __restrict__ beta, int dprev,
    __half2* __restrict__ aggh2)
{
    int gw = (blockIdx.x * 256 + threadIdx.x) >> 6;   // one wave per atom
    int lane = threadIdx.x & 63;
    float e1 = 1.0f + eps_param[d];

    float2 sc = make_float2(0.f, 0.f), sh = make_float2(0.f, 0.f);
    if (BN) {
        const float inv_n = 1.0f / (float)N_ATOMS;
        int c0 = lane * 2;
        float m0 = s1[c0] * inv_n;
        float v0 = fmaxf(s2[c0] * inv_n - m0 * m0, 0.f);
        float m1 = s1[c0 + 1] * inv_n;
        float v1 = fmaxf(s2[c0 + 1] * inv_n - m1 * m1, 0.f);
        sc.x = gamma[dprev * 128 + c0]     * rsqrtf(v0 + BN_EPS);
        sc.y = gamma[dprev * 128 + c0 + 1] * rsqrtf(v1 + BN_EPS);
        sh.x = beta[dprev * 128 + c0]     - m0 * sc.x;
        sh.y = beta[dprev * 128 + c0 + 1] - m1 * sc.y;
    }

    float2 a = __half22float2(xh2[(size_t)gw * 64 + lane]);
    if (BN) {
        a.x = fmaxf(a.x * sc.x + sh.x, 0.f);
        a.y = fmaxf(a.y * sc.y + sh.y, 0.f);
    }
    float2 acc;
    acc.x = a.x * e1;
    acc.y = a.y * e1;

    int s = rowptr[gw], e = rowptr[gw + 1];
    for (int i = s; i < e; i += 8) {
        #pragma unroll
        for (int u = 0; u < 8; ++u) {
            int idx = i + u;
            int c = col[min(idx, e - 1)];
            float2 f = __half22float2(xh2[(size_t)c * 64 + lane]);
            if (BN) {
                f.x = fmaxf(f.x * sc.x + sh.x, 0.f);
                f.y = fmaxf(f.y * sc.y + sh.y, 0.f);
            }
            if (idx < e) {
                acc.x += f.x;
                acc.y += f.y;
            }
        }
    }
    aggh2[(size_t)gw * 64 + lane] = __float22half2_rn(acc);
}

// ---------------- per-molecule mean pooling with fused BN+ReLU ----------------
__global__ void pool_kernel(const __half* __restrict__ hh, const int* __restrict__ off,
                            const float* __restrict__ s1, const float* __restrict__ s2,
                            const float* __restrict__ gamma, const float* __restrict__ beta,
                            int dprev, float* __restrict__ out)
{
    int m = blockIdx.x;
    int c = threadIdx.x;
    const float inv_n = 1.0f / (float)N_ATOMS;
    float mean = s1[c] * inv_n;
    float var = fmaxf(s2[c] * inv_n - mean * mean, 0.f);
    float sc = gamma[dprev * 128 + c] * rsqrtf(var + BN_EPS);
    float sh = beta[dprev * 128 + c] - mean * sc;
    int s = off[m], e = off[m + 1];
    float acc = 0.f;
    for (int r = s; r < e; ++r) {
        float v = __half2float(hh[(size_t)r * 128 + c]);
        acc += fmaxf(v * sc + sh, 0.f);
    }
    int cnt = e - s;
    out[m * 128 + c] = (cnt > 0) ? acc / (float)cnt : 0.f;
}

// ---------------- launcher ----------------
extern "C" void kernel_launch(void* const* d_in, const int* in_sizes, int n_in,
                              void* d_out, int out_size, void* d_ws, size_t ws_size,
                              hipStream_t stream)
{
    const float* f_atoms   = (const float*)d_in[0];
    const float* W_in      = (const float*)d_in[1];
    const float* b_in      = (const float*)d_in[2];
    const float* W1        = (const float*)d_in[3];
    const float* b1        = (const float*)d_in[4];
    const float* W2        = (const float*)d_in[5];
    const float* b2        = (const float*)d_in[6];
    const float* gamma     = (const float*)d_in[7];
    const float* beta      = (const float*)d_in[8];
    const float* eps_param = (const float*)d_in[9];
    const int*   edge_index= (const int*)d_in[10];
    const int*   seg       = (const int*)d_in[11];
    const int*   src = edge_index;
    const int*   tgt = edge_index + N_EDGES;
    float* out = (float*)d_out;

    char* ws = (char*)d_ws;
    size_t off = 0;
    auto alloc = [&](size_t bytes) -> char* {
        char* p = ws + off;
        off += (bytes + 255) & ~(size_t)255;
        return p;
    };
    __half* xh    = (__half*)alloc((size_t)N_ATOMS * HIDDEN * 2);   // x0 = relu(proj)
    __half* aggh  = (__half*)alloc((size_t)N_ATOMS * HIDDEN * 2);   // aggregate out
    __half* hpre  = (__half*)alloc((size_t)N_ATOMS * HIDDEN * 2);   // mlp out (pre-BN h)
    __half* Ah    = (__half*)alloc((size_t)N_ATOMS * K_IN_PAD * 2);
    __half* Wt    = (__half*)alloc((size_t)(128 * K_IN_PAD + 2 * DEPTH * 128 * 128) * 2);
    int*   rowptr = (int*)alloc((N_ATOMS + 1) * 4);
    int*   wcur   = (int*)alloc(N_ATOMS * 4);
    int*   partial= (int*)alloc(N_ATOMS * 4);
    int*   bsum   = (int*)alloc(256 * 4);
    unsigned short* col = (unsigned short*)alloc((size_t)N_EDGES * 2);
    float* s12    = (float*)alloc(DEPTH * 256 * 4);
    int*   moloff = (int*)alloc((N_MOLS + 1) * 4);

    const __half* Wt_in = Wt;
    const __half* W1t   = Wt + 128 * K_IN_PAD;
    const __half* W2t   = W1t + DEPTH * 128 * 128;

    // ---- CSR build ----
    hipMemsetAsync(wcur, 0, N_ATOMS * 4, stream);
    hist_kernel<<<(N_EDGES + 255) / 256, 256, 0, stream>>>(tgt, N_EDGES, wcur);
    const int NB = (N_ATOMS + 255) / 256;   // 196
    scan_block_kernel<<<NB, 256, 0, stream>>>(wcur, partial, bsum, N_ATOMS);
    scan_top_kernel<<<1, 256, 0, stream>>>(bsum, NB);
    scan_add_kernel<<<NB, 256, 0, stream>>>(partial, bsum, rowptr, wcur, N_ATOMS, N_EDGES);
    fill_csr_kernel<<<(N_EDGES + 255) / 256, 256, 0, stream>>>(src, tgt, N_EDGES, wcur, col);

    // ---- fused setup ----
    {
        const int NCH = N_ATOMS * (K_IN_PAD / 4);
        const int NW4 = (128 * K_IN_PAD + 2 * DEPTH * 128 * 128) / 4;
        const int TOT = NCH + NW4 + N_MOLS + 1;
        setup_kernel<<<(TOT + 255) / 256, 256, 0, stream>>>(
            f_atoms, W_in, W1, W2, seg, Ah, Wt, s12, moloff);
    }

    // ---- input projection + ReLU -> fp16 x0 ----
    const int GB = (N_ATOMS + 127) / 128;   // 391
    mfma_gemm<true><<<GB, 256, 0, stream>>>(Ah, Wt_in, b_in, xh, N_ATOMS, K_IN_PAD);

    for (int d = 0; d < DEPTH; ++d) {
        float* s1d = s12 + d * 256;
        float* s2d = s1d + 128;
        if (d == 0) {
            aggregate_kernel<false><<<N_ATOMS / 4, 256, 0, stream>>>(
                (const __half2*)xh, rowptr, col, eps_param, d,
                nullptr, nullptr, nullptr, nullptr, 0, (__half2*)aggh);
        } else {
            float* s1p = s12 + (d - 1) * 256;
            float* s2p = s1p + 128;
            aggregate_kernel<true><<<N_ATOMS / 4, 256, 0, stream>>>(
                (const __half2*)hpre, rowptr, col, eps_param, d,
                s1p, s2p, gamma, beta, d - 1, (__half2*)aggh);
        }
        mlp_fused<<<GB, 256, 0, stream>>>(
            aggh, W1t + (size_t)d * 128 * 128, W2t + (size_t)d * 128 * 128,
            b1 + d * HIDDEN, b2 + d * HIDDEN, hpre, N_ATOMS, s1d, s2d);
    }

    pool_kernel<<<N_MOLS, 128, 0, stream>>>(
        hpre, moloff, s12 + (DEPTH - 1) * 256, s12 + (DEPTH - 1) * 256 + 128,
        gamma, beta, DEPTH - 1, out);
}